// Round 5
// baseline (2646.250 us; speedup 1.0000x reference)
//
#include <hip/hip_runtime.h>

// gamma_{t+1}[j] = clip(sum_e w[e]*gamma_t[nbr[e]] + residual[j], 0, 1), 10 steps.
// R5: block-local bucket reorder (block = 256 contiguous rows = contiguous edge
// span). Edges regrouped by neighbor bucket (8192 gammas = 32KB LDS slice) with
// NO global atomics and append-sequential writes. Step kernel stages each slice
// in LDS and does edge-parallel coalesced walks: contrib accumulated into
// per-row LDS f32 via ds_add_f32. No random L2 gathers anywhere.
// Edge pack u32: [31:24]=row_in_block, [23:13]=q (bl*2^18, bl<2^-7), [12:0]=local idx.

#define RPB    256                     // rows per block
#define BSHIFT 13
#define SLICE  8192                    // floats per gamma slice (32 KB)
#define LMASK  8191u
#define QSCALE 262144.0f               // 2^18
#define QINV   3.814697265625e-06f    // 2^-18
#define QMAX   2047u
#define MAXNB  32

// row_ptr[j] = first edge index with seg >= j.
__global__ void build_rowptr(const int* __restrict__ seg, int* __restrict__ row_ptr,
                             int n_edges, int n_part) {
    int e = blockIdx.x * blockDim.x + threadIdx.x;
    if (e >= n_edges) return;
    int s = seg[e];
    int sprev = (e == 0) ? -1 : seg[e - 1];
    for (int j = sprev + 1; j <= s; ++j) row_ptr[j] = e;
    if (e == n_edges - 1)
        for (int j = s + 1; j <= n_part; ++j) row_ptr[j] = n_edges;
}

// Per row-block: count per bucket, local scan, scatter (block-exclusive span),
// fused residual + gamma1 (= clip(residual), since gamma0 == 0).
__global__ __launch_bounds__(256) void reorder_kernel(
        const float* __restrict__ bl, const int* __restrict__ nbr,
        const int* __restrict__ seg, const int* __restrict__ row_ptr,
        unsigned* __restrict__ epack, int* __restrict__ bnd,
        float* __restrict__ residual, float* __restrict__ g1,
        int n_part, int nb) {
    __shared__ unsigned cnt[MAXNB];
    __shared__ unsigned cur[MAXNB];
    __shared__ unsigned accq[RPB];
    int rb = blockIdx.x;
    int tid = threadIdx.x;
    int row_lo = rb * RPB;
    int row_hi = min(row_lo + RPB, n_part);
    int nrows = row_hi - row_lo;
    if (tid < nb) cnt[tid] = 0;
    if (tid < nrows) accq[tid] = 0;
    int e_lo = row_ptr[row_lo];
    int e_hi = row_ptr[row_hi];
    __syncthreads();
    for (int e = e_lo + tid; e < e_hi; e += 256)
        atomicAdd(&cnt[((unsigned)nbr[e]) >> BSHIFT], 1u);
    __syncthreads();
    if (tid == 0) {
        unsigned run = (unsigned)e_lo;
        for (int b = 0; b < nb; b++) {
            cur[b] = run;
            bnd[rb * (nb + 1) + b] = (int)run;
            run += cnt[b];
        }
        bnd[rb * (nb + 1) + nb] = (int)run;   // == e_hi
    }
    __syncthreads();
    for (int e = e_lo + tid; e < e_hi; e += 256) {
        unsigned v = (unsigned)nbr[e];
        unsigned b = v >> BSHIFT;
        unsigned q = (unsigned)(bl[e] * QSCALE + 0.5f);
        q = q > QMAX ? QMAX : q;
        unsigned r = (unsigned)(seg[e] - row_lo);
        unsigned pos = atomicAdd(&cur[b], 1u);
        epack[pos] = (r << 24) | (q << 13) | (v & LMASK);
        atomicAdd(&accq[r], q);
    }
    __syncthreads();
    if (tid < nrows) {
        float res = 1.0f - (float)accq[tid] * QINV;
        residual[row_lo + tid] = res;
        g1[row_lo + tid] = fminf(fmaxf(res, 0.0f), 1.0f);
    }
}

// One step: loop buckets; stage gamma slice in LDS; edge-parallel coalesced walk;
// per-row accumulation via LDS float atomics.
__global__ __launch_bounds__(256) void step_lds(
        const float* __restrict__ gamma_in, const unsigned* __restrict__ epack,
        const int* __restrict__ bnd, const float* __restrict__ residual,
        float* __restrict__ gamma_out, int n_part, int nb) {
    __shared__ float slice[SLICE];
    __shared__ float acc[RPB];
    int rb = blockIdx.x;
    int tid = threadIdx.x;
    acc[tid] = 0.0f;
    const int* mybnd = bnd + rb * (nb + 1);
    int e0 = mybnd[0];
    for (int b = 0; b < nb; b++) {
        int base = b << BSHIFT;
        int e1 = mybnd[b + 1];
        __syncthreads();           // slice from prev iter fully consumed
        int lim = n_part - base;   // valid elements in this slice
        for (int i = tid * 4; i < SLICE; i += 1024) {
            if (i + 3 < lim) {
                *(float4*)(slice + i) = *(const float4*)(gamma_in + base + i);
            } else {
                #pragma unroll
                for (int k = 0; k < 4; k++)
                    slice[i + k] = (i + k < lim) ? gamma_in[base + i + k] : 0.0f;
            }
        }
        __syncthreads();
        for (int e = e0 + tid; e < e1; e += 256) {
            unsigned p = epack[e];
            float w = (float)((p >> 13) & QMAX);
            float g = slice[p & LMASK];
            atomicAdd(&acc[p >> 24], w * g);
        }
        e0 = e1;
    }
    __syncthreads();
    int row = rb * RPB + tid;
    if (row < n_part) {
        float gv = acc[tid] * QINV + residual[row];
        gamma_out[row] = fminf(fmaxf(gv, 0.0f), 1.0f);
    }
}

// ---------- fallback (ws too small): R4 raw path ----------
__global__ void residual_raw(const float* __restrict__ bl,
                             const int* __restrict__ row_ptr,
                             float* __restrict__ residual, float* __restrict__ g1,
                             int n_part) {
    int idx  = blockIdx.x * blockDim.x + threadIdx.x;
    int row  = idx >> 6;
    int lane = threadIdx.x & 63;
    if (row >= n_part) return;
    int start = row_ptr[row], end = row_ptr[row + 1];
    float acc = 0.0f;
    for (int e = start + lane; e < end; e += 64) acc += bl[e];
    #pragma unroll
    for (int off = 32; off > 0; off >>= 1) acc += __shfl_down(acc, off);
    if (lane == 0) {
        float r = 1.0f - acc;
        residual[row] = r;
        g1[row] = fminf(fmaxf(r, 0.0f), 1.0f);
    }
}

__global__ __launch_bounds__(256) void step4_raw(const float* __restrict__ gamma_in,
                                                 const float* __restrict__ bl,
                                                 const int* __restrict__ nbr,
                                                 const int* __restrict__ row_ptr,
                                                 const float* __restrict__ residual,
                                                 float* __restrict__ gamma_out, int n_part) {
    int tid = blockIdx.x * 256 + threadIdx.x;
    int row = tid >> 2;
    int sub = tid & 3;
    if (row >= n_part) return;
    int start = row_ptr[row], end = row_ptr[row + 1];
    float acc = 0.0f;
    for (int j = start + sub; j < end; j += 4)
        acc += bl[j] * gamma_in[nbr[j]];
    acc += __shfl_down(acc, 2);
    acc += __shfl_down(acc, 1);
    if (sub == 0) {
        float g = acc + residual[row];
        gamma_out[row] = fminf(fmaxf(g, 0.0f), 1.0f);
    }
}

extern "C" void kernel_launch(void* const* d_in, const int* in_sizes, int n_in,
                              void* d_out, int out_size, void* d_ws, size_t ws_size,
                              hipStream_t stream) {
    const float* bl  = (const float*)d_in[1];
    const int*   nbr = (const int*)d_in[2];
    const int*   seg = (const int*)d_in[3];
    const int n_part  = in_sizes[0];
    const int n_edges = in_sizes[1];
    const int horizon = 10;
    float* gout = (float*)d_out;
    const int BLK = 256;

    const int n_rb = (n_part + RPB - 1) / RPB;          // 782 row-blocks
    const int nb   = (n_part + SLICE - 1) >> BSHIFT;    // 25 buckets

    auto align256 = [](size_t x) { return (x + 255) & ~(size_t)255; };
    char* ws = (char*)d_ws;
    size_t off = 0;
    int* row_ptr = (int*)(ws + off);      off += align256((size_t)(n_part + 1) * 4);
    float* residual = (float*)(ws + off); off += align256((size_t)n_part * 4);
    float* bufX = (float*)(ws + off);     off += align256((size_t)n_part * 4);
    int* bnd = (int*)(ws + off);          off += align256((size_t)n_rb * (nb + 1) * 4);
    unsigned* epack = (unsigned*)(ws + off);
    size_t need = off + align256((size_t)(n_edges + 4) * 4);
    bool ok = (ws_size >= need) && (nb <= MAXNB);

    build_rowptr<<<dim3((n_edges + BLK - 1) / BLK), dim3(BLK), 0, stream>>>(
        seg, row_ptr, n_edges, n_part);

    if (ok) {
        reorder_kernel<<<dim3(n_rb), dim3(256), 0, stream>>>(
            bl, nbr, seg, row_ptr, epack, bnd, residual, bufX, n_part, nb);
        // ping-pong bufX <-> gout; t=1 result (gamma1) is in bufX; horizon=10 even
        // -> t=10 lands in gout.
        const float* cur = bufX;
        for (int t = 2; t <= horizon; ++t) {
            float* dst = (t & 1) ? bufX : gout;
            step_lds<<<dim3(n_rb), dim3(256), 0, stream>>>(
                cur, epack, bnd, residual, dst, n_part, nb);
            cur = dst;
        }
        if (cur != gout)
            hipMemcpyAsync(gout, cur, (size_t)n_part * 4, hipMemcpyDeviceToDevice, stream);
    } else {
        int wave_row_blocks = (n_part * 64 + BLK - 1) / BLK;
        residual_raw<<<dim3(wave_row_blocks), dim3(BLK), 0, stream>>>(
            bl, row_ptr, residual, bufX, n_part);
        int step_blocks = (n_part * 4 + BLK - 1) / BLK;
        const float* cur = bufX;
        for (int t = 2; t <= horizon; ++t) {
            float* dst = (t & 1) ? bufX : gout;
            step4_raw<<<dim3(step_blocks), dim3(BLK), 0, stream>>>(
                cur, bl, nbr, row_ptr, residual, dst, n_part);
            cur = dst;
        }
        if (cur != gout)
            hipMemcpyAsync(gout, cur, (size_t)n_part * 4, hipMemcpyDeviceToDevice, stream);
    }
}

// Round 7
// 1740.115 us; speedup vs baseline: 1.5207x; 1.5207x over previous
//
#include <hip/hip_runtime.h>

// gamma_{t+1}[j] = clip(sum_e bl[e]*gamma_t[nbr[e]] + residual[j], 0, 1), 10 steps.
// R6b: no packing/quantization (minimize per-edge VALU). Step: 4 lanes/row,
// nontemporal 16B stream loads (keep L1 for gamma gathers), 4 independent
// gathers + 4 fmac per lane-iter. gamma0 == 0 => gamma1 = clip(residual).
// Uses ext_vector_type (true vector types) for the nontemporal builtins.

typedef float fx4 __attribute__((ext_vector_type(4)));
typedef int   ix4 __attribute__((ext_vector_type(4)));

// row_ptr[j] = first edge index with seg >= j.
__global__ void build_rowptr(const int* __restrict__ seg, int* __restrict__ row_ptr,
                             int n_edges, int n_part) {
    int e = blockIdx.x * blockDim.x + threadIdx.x;
    if (e >= n_edges) return;
    int s = seg[e];
    int sprev = (e == 0) ? -1 : seg[e - 1];
    for (int j = sprev + 1; j <= s; ++j) row_ptr[j] = e;
    if (e == n_edges - 1)
        for (int j = s + 1; j <= n_part; ++j) row_ptr[j] = n_edges;
}

// residual[r] = 1 - sum(bl) over row r; gamma1[r] = clip(residual[r]).
__global__ void residual_g1(const float* __restrict__ bl,
                            const int* __restrict__ row_ptr,
                            float* __restrict__ residual, float* __restrict__ g1,
                            int n_part) {
    int idx  = blockIdx.x * blockDim.x + threadIdx.x;
    int row  = idx >> 6;
    int lane = threadIdx.x & 63;
    if (row >= n_part) return;
    int start = row_ptr[row], end = row_ptr[row + 1];
    float acc = 0.0f;
    for (int e = start + lane; e < end; e += 64) acc += bl[e];
    #pragma unroll
    for (int off = 32; off > 0; off >>= 1) acc += __shfl_down(acc, off);
    if (lane == 0) {
        float r = 1.0f - acc;
        residual[row] = r;
        g1[row] = fminf(fmaxf(r, 0.0f), 1.0f);
    }
}

// One step: 4 lanes/row; aligned 16B nontemporal stream loads;
// 4 independent gathers per lane-iteration; fmac-only math.
__global__ __launch_bounds__(256) void step_raw(const float* __restrict__ gamma_in,
                                                const float* __restrict__ bl,
                                                const int* __restrict__ nbr,
                                                const int* __restrict__ row_ptr,
                                                const float* __restrict__ residual,
                                                float* __restrict__ gamma_out, int n_part) {
    int tid = blockIdx.x * 256 + threadIdx.x;
    int row = tid >> 2;
    int sub = tid & 3;
    if (row >= n_part) return;
    int start = row_ptr[row], end = row_ptr[row + 1];
    float acc = 0.0f;
    int abase = (start + 3) & ~3;          // first 16B-aligned quad boundary
    {   // head (< 3 edges): one edge per sub-lane
        int j = start + sub;
        if (j < abase && j < end)
            acc += bl[j] * gamma_in[nbr[j]];
    }
    int i = abase + sub * 4;
    #pragma unroll 2
    for (; i + 3 < end; i += 16) {
        fx4 b = __builtin_nontemporal_load((const fx4*)(bl + i));
        ix4 v = __builtin_nontemporal_load((const ix4*)(nbr + i));
        float g0 = gamma_in[v.x];
        float g1 = gamma_in[v.y];
        float g2 = gamma_in[v.z];
        float g3 = gamma_in[v.w];
        acc += b.x * g0 + b.y * g1 + b.z * g2 + b.w * g3;
    }
    for (int j = i; j < end && j < i + 4; ++j)   // tail: partial quad
        acc += bl[j] * gamma_in[nbr[j]];
    acc += __shfl_down(acc, 2);
    acc += __shfl_down(acc, 1);
    if (sub == 0) {
        float g = acc + residual[row];
        __builtin_nontemporal_store(fminf(fmaxf(g, 0.0f), 1.0f), gamma_out + row);
    }
}

extern "C" void kernel_launch(void* const* d_in, const int* in_sizes, int n_in,
                              void* d_out, int out_size, void* d_ws, size_t ws_size,
                              hipStream_t stream) {
    const float* bl  = (const float*)d_in[1];
    const int*   nbr = (const int*)d_in[2];
    const int*   seg = (const int*)d_in[3];
    const int n_part  = in_sizes[0];
    const int n_edges = in_sizes[1];
    const int horizon = 10;
    float* gout = (float*)d_out;
    const int BLK = 256;

    auto align256 = [](size_t x) { return (x + 255) & ~(size_t)255; };
    char* ws = (char*)d_ws;
    size_t off = 0;
    int* row_ptr = (int*)(ws + off);      off += align256((size_t)(n_part + 1) * 4);
    float* residual = (float*)(ws + off); off += align256((size_t)n_part * 4);
    float* bufX = (float*)(ws + off);     off += align256((size_t)n_part * 4);

    build_rowptr<<<dim3((n_edges + BLK - 1) / BLK), dim3(BLK), 0, stream>>>(
        seg, row_ptr, n_edges, n_part);

    int wave_row_blocks = (n_part * 64 + BLK - 1) / BLK;
    residual_g1<<<dim3(wave_row_blocks), dim3(BLK), 0, stream>>>(
        bl, row_ptr, residual, bufX, n_part);

    // t=1 (gamma1) is in bufX. Steps t=2..10: even t -> gout, odd t -> bufX;
    // horizon=10 lands in gout; src != dst at every step.
    int step_blocks = (n_part * 4 + BLK - 1) / BLK;
    const float* cur = bufX;
    for (int t = 2; t <= horizon; ++t) {
        float* dst = (t & 1) ? bufX : gout;
        step_raw<<<dim3(step_blocks), dim3(BLK), 0, stream>>>(
            cur, bl, nbr, row_ptr, residual, dst, n_part);
        cur = dst;
    }
    if (cur != gout)
        (void)hipMemcpyAsync(gout, cur, (size_t)n_part * 4, hipMemcpyDeviceToDevice, stream);
}